// Round 6
// baseline (798.202 us; speedup 1.0000x reference)
//
#include <hip/hip_runtime.h>

// voltageNN R7: R4 single-wave-per-(layer,batch) frame (proven 492us kernel)
// with two targeted cuts:
//  1. rcp-merge algebra: sig(a)*tanh(b) = (1-Eb)/[(1+Ea)(1+Eb)] applied to
//     i*g and o*tanh(c); cell state kept pre-scaled by -2log2e. 40 -> 32
//     transcendentals per step.
//  2. per-step sentinel dataflow: seq poisoned with 0xFFFFFFFF (NaN bits no
//     finite h can produce); producer fire-and-forget relaxed-agent store per
//     step; consumer prefetches x(t+1) one step ahead, spins only if caught
//     up. Pipeline fill 160 steps -> ~4 steps. Deletes flags, readlane-bcast,
//     and the chunk machinery.
// Head stays a separate kernel (R6 fusion regressed). No launch_bounds min
// (R6 showed VGPR=40 regardless; state lives in AGPRs).

#define LAYERS 5
#define TT 1000
#define BATCH 128
#define POISON 0xFFFFFFFFu

#define LOG2E 1.4426950408889634f

__device__ __forceinline__ float fast_exp2(float x) {
#if __has_builtin(__builtin_amdgcn_exp2f)
  return __builtin_amdgcn_exp2f(x);
#else
  return __exp2f(x);
#endif
}
__device__ __forceinline__ float fast_rcp(float x) {
#if __has_builtin(__builtin_amdgcn_rcpf)
  return __builtin_amdgcn_rcpf(x);
#else
  return 1.0f / x;
#endif
}
// sigmoid for the MLP head (unscaled weights there)
__device__ __forceinline__ float fast_sigmoid(float z) {
  float e = fast_exp2(-LOG2E * z);
  return fast_rcp(1.0f + e);
}

template <int CTRL>
__device__ __forceinline__ float dpp_add(float v) {
  int moved = __builtin_amdgcn_update_dpp(0, __builtin_bit_cast(int, v),
                                          CTRL, 0xF, 0xF, false);
  return v + __builtin_bit_cast(float, moved);
}

// Wave64 total, returned wave-uniform (SGPR via readlane 63).
__device__ __forceinline__ float wave_sum_uniform(float v) {
  v = dpp_add<0x128>(v);  // row_ror:8
  v = dpp_add<0x124>(v);  // row_ror:4
  v = dpp_add<0x122>(v);  // row_ror:2
  v = dpp_add<0x121>(v);  // row_ror:1
  v = dpp_add<0x142>(v);  // row_bcast:15
  v = dpp_add<0x143>(v);  // row_bcast:31
  return __builtin_bit_cast(float, __builtin_amdgcn_readlane(__builtin_bit_cast(int, v), 63));
}

__device__ __forceinline__ unsigned int agent_load_u32(const unsigned int* p) {
  return __hip_atomic_load(p, __ATOMIC_RELAXED, __HIP_MEMORY_SCOPE_AGENT);
}

__global__ __launch_bounds__(64) void lstm_wave_kernel(
    const float* __restrict__ x,     // [B, T]
    const float* __restrict__ Wih,   // [L, 1024]
    const float* __restrict__ Whh,   // [L, 1024]
    const float* __restrict__ bih,   // [L, 1024]
    const float* __restrict__ bhh,   // [L, 1024]
    const float* __restrict__ Whr,   // [L, 256]
    float* __restrict__ seq)         // [L, B, T] layer outputs (workspace)
{
  const int bid  = blockIdx.x;
  const int l    = bid >> 7;   // bid / 128
  const int b    = bid & 127;  // bid % 128
  const int lane = threadIdx.x;

  // per-lane weights, pre-scaled into the exp2 domain.
  // gate order: 0=i, 1=f, 2=g(tanh), 3=o.  E[g] = exp2(sc*(pre-activation))
  // with sc = -log2e for sigmoid gates, -2log2e for the tanh gate.
  float wix[4][4], whx[4][4], gb[4][4], whr[4], cc[4];
  const int base = l * 1024;
#pragma unroll
  for (int g = 0; g < 4; ++g) {
    const float sc = (g == 2) ? (-2.0f * LOG2E) : (-LOG2E);
#pragma unroll
    for (int k = 0; k < 4; ++k) {
      int j = base + g * 256 + k * 64 + lane;
      wix[g][k] = Wih[j] * sc;
      whx[g][k] = Whh[j] * sc;
      gb[g][k]  = (bih[j] + bhh[j]) * sc;
    }
  }
#pragma unroll
  for (int k = 0; k < 4; ++k) {
    whr[k] = Whr[l * 256 + k * 64 + lane];
    cc[k] = 0.0f;  // scaled cell state: cc = -2*log2e * c
  }

  const unsigned int* in =
      (const unsigned int*)((l == 0) ? (x + b * TT)
                                     : (seq + ((l - 1) * BATCH + b) * TT));
  float* outp = seq + (l * BATCH + b) * TT;

  const float P2C = 2.0f * LOG2E;

  // resolve x(0); prefetch x(1).  All lanes load the same address -> the
  // value is wave-uniform in a VGPR (no bcast needed).  For l==0 the input
  // is finite floats, so the POISON test never triggers and the same code
  // path serves all layers.
  unsigned int v0 = agent_load_u32(in);
  while (v0 == POISON) v0 = agent_load_u32(in);
  float xs = __builtin_bit_cast(float, v0);
  unsigned int pf = agent_load_u32(in + 1);

  float h = 0.0f;
#pragma unroll 2
  for (int t = 0; t < TT; ++t) {
    // 16 pre-activations -> exp2 (all independent)
    float E[4][4];
#pragma unroll
    for (int g = 0; g < 4; ++g)
#pragma unroll
      for (int k = 0; k < 4; ++k)
        E[g][k] = fast_exp2(fmaf(h, whx[g][k], fmaf(xs, wix[g][k], gb[g][k])));

    // gate combines with merged reciprocals (k's independent):
    //   i*g       = (1-E2)/[(1+E0)(1+E2)]          (1 rcp instead of 2)
    //   o*tanh(c) = (1-Et)/[(1+E3)(1+Et)]          (1 rcp instead of 2)
    float rr[4];
#pragma unroll
    for (int k = 0; k < 4; ++k) {
      float A0 = 1.0f + E[0][k];
      float A1 = 1.0f + E[1][k];
      float A2 = 1.0f + E[2][k];
      float A3 = 1.0f + E[3][k];
      float fg  = fast_rcp(A1);                  // f
      float D02 = fast_rcp(A0 * A2);
      float t2  = fmaf(P2C, E[2][k], -P2C);      // -2log2e*(1-E2)
      cc[k] = fmaf(fg, cc[k], t2 * D02);         // cc = -2log2e * c
      float Et  = fast_exp2(cc[k]);              // e^{-2c}
      float D3t = fast_rcp(A3 * (1.0f + Et));
      rr[k] = fmaf(-Et, whr[k], whr[k]) * D3t;   // o*tanh(c)*whr
    }
    float r = (rr[0] + rr[1]) + (rr[2] + rr[3]);

    h = wave_sum_uniform(r);     // SGPR-uniform h(t)

    // fire-and-forget publish (word carries data + readiness; no fence).
    if (lane == 0) {
      if (l < 4)
        __hip_atomic_store((unsigned int*)(outp + t),
                           __builtin_bit_cast(unsigned int, h),
                           __ATOMIC_RELAXED, __HIP_MEMORY_SCOPE_AGENT);
      else
        outp[t] = h;  // consumed by the head kernel after this kernel ends
    }

    // advance prefetch: resolve x(t+1) (usually already valid), issue x(t+2).
    if (t + 1 < TT) {
      unsigned int v = pf;
      while (v == POISON) v = agent_load_u32(in + t + 1);
      xs = __builtin_bit_cast(float, v);
      if (t + 2 < TT) pf = agent_load_u32(in + t + 2);
    }
  }
}

__global__ __launch_bounds__(256) void mlp_head_kernel(
    const float* __restrict__ seq4,  // [B, T] layer-4 outputs
    const float* __restrict__ W1, const float* __restrict__ b1,
    const float* __restrict__ W2, const float* __restrict__ b2,
    const float* __restrict__ W3, const float* __restrict__ b3,
    const float* __restrict__ W4, const float* __restrict__ b4,
    float* __restrict__ out)         // [B]
{
  __shared__ float sx[TT];
  __shared__ float sh[100];
  __shared__ float sh2[100];
  __shared__ float part[100];
  __shared__ float red[4];

  const int b = blockIdx.x, tid = threadIdx.x;
  for (int i = tid; i < TT; i += 256) sx[i] = seq4[b * TT + i];
  __syncthreads();

  // phase 1: 2 threads per output (tid<100: t in [0,500); tid in [128,228): [500,1000))
  const int half = (tid >= 128) ? 1 : 0;
  const int oid  = half ? (tid - 128) : tid;
  float myacc = 0.0f;
  if (oid < 100) {
    const float* w  = W1 + oid * TT + half * 500;
    const float* xx = sx + half * 500;
    float a0 = 0.f, a1 = 0.f, a2 = 0.f, a3 = 0.f;
    for (int t0 = 0; t0 < 500; t0 += 4) {
      float4 v = *(const float4*)(w + t0);
      a0 = fmaf(v.x, xx[t0 + 0], a0);
      a1 = fmaf(v.y, xx[t0 + 1], a1);
      a2 = fmaf(v.z, xx[t0 + 2], a2);
      a3 = fmaf(v.w, xx[t0 + 3], a3);
    }
    myacc = (a0 + a1) + (a2 + a3);
    if (half) part[oid] = myacc;
  }
  __syncthreads();
  if (tid < 100) sh[tid] = fast_sigmoid(myacc + part[tid] + b1[tid]);
  __syncthreads();

  if (tid < 100) {
    float acc = b2[tid];
    const float* w = W2 + tid * 100;
    for (int k = 0; k < 100; ++k) acc += w[k] * sh[k];
    sh2[tid] = fast_sigmoid(acc);
  }
  __syncthreads();

  if (tid < 100) {
    float acc = b3[tid];
    const float* w = W3 + tid * 100;
    for (int k = 0; k < 100; ++k) acc += w[k] * sh2[k];
    sh[tid] = fmaxf(acc, 0.0f);
  }
  __syncthreads();

  float r = (tid < 100) ? sh[tid] * W4[tid] : 0.0f;
  r = dpp_add<0x128>(r);
  r = dpp_add<0x124>(r);
  r = dpp_add<0x122>(r);
  r = dpp_add<0x121>(r);
  r = dpp_add<0x142>(r);
  r = dpp_add<0x143>(r);
  r = __builtin_bit_cast(float, __builtin_amdgcn_readlane(__builtin_bit_cast(int, r), 63));
  if ((tid & 63) == 0) red[tid >> 6] = r;
  __syncthreads();
  if (tid == 0) out[b] = (red[0] + red[1]) + (red[2] + red[3]) + b4[0];
}

extern "C" void kernel_launch(void* const* d_in, const int* in_sizes, int n_in,
                              void* d_out, int out_size, void* d_ws, size_t ws_size,
                              hipStream_t stream) {
  const float* x   = (const float*)d_in[0];
  const float* Wih = (const float*)d_in[1];
  const float* Whh = (const float*)d_in[2];
  const float* bih = (const float*)d_in[3];
  const float* bhh = (const float*)d_in[4];
  const float* Whr = (const float*)d_in[5];
  const float* W1  = (const float*)d_in[6];
  const float* b1  = (const float*)d_in[7];
  const float* W2  = (const float*)d_in[8];
  const float* b2  = (const float*)d_in[9];
  const float* W3  = (const float*)d_in[10];
  const float* b3  = (const float*)d_in[11];
  const float* W4  = (const float*)d_in[12];
  const float* b4  = (const float*)d_in[13];

  float* seq = (float*)d_ws;  // [5][128][1000] f32

  // poison layers 0..3 (the sentinel-consumed regions); layer 4 is plain.
  hipMemsetAsync(seq, 0xFF, (LAYERS - 1) * BATCH * TT * sizeof(float), stream);
  lstm_wave_kernel<<<LAYERS * BATCH, 64, 0, stream>>>(x, Wih, Whh, bih, bhh,
                                                      Whr, seq);
  mlp_head_kernel<<<BATCH, 256, 0, stream>>>(seq + 4 * BATCH * TT,
                                             W1, b1, W2, b2, W3, b3, W4, b4,
                                             (float*)d_out);
}

// Round 8
// 688.170 us; speedup vs baseline: 1.1599x; 1.1599x over previous
//
#include <hip/hip_runtime.h>

// voltageNN R8: proven R4 communication frame (chunked flags, per-chunk
// gather/publish -- R7's per-step sentinel poll put a ~700cyc cross-XCD
// round-trip on the chain every step: FETCH 3->31MB, 492->710us. Reverted.)
// Kept from R7: rcp-merge algebra (sig(a)*tanh(b) = (1-Eb)/[(1+Ea)(1+Eb)]
// for i*g and o*tanh(c); cell pre-scaled by -2log2e) -> 40 -> 32
// transcendentals/step. New: CH 40 -> 20 (pipeline fill 160 -> 80 steps,
// +25 chunk boundaries; net ~ -19us predicted).

#define LAYERS 5
#define TT 1000
#define BATCH 128
#define CH 20            // chunk length (divides TT)
#define NCH (TT / CH)    // 50 chunks

#define LOG2E 1.4426950408889634f

__device__ __forceinline__ float fast_exp2(float x) {
#if __has_builtin(__builtin_amdgcn_exp2f)
  return __builtin_amdgcn_exp2f(x);
#else
  return __exp2f(x);
#endif
}
__device__ __forceinline__ float fast_rcp(float x) {
#if __has_builtin(__builtin_amdgcn_rcpf)
  return __builtin_amdgcn_rcpf(x);
#else
  return 1.0f / x;
#endif
}
// sigmoid for the MLP head (unscaled weights there)
__device__ __forceinline__ float fast_sigmoid(float z) {
  float e = fast_exp2(-LOG2E * z);
  return fast_rcp(1.0f + e);
}

template <int CTRL>
__device__ __forceinline__ float dpp_add(float v) {
  int moved = __builtin_amdgcn_update_dpp(0, __builtin_bit_cast(int, v),
                                          CTRL, 0xF, 0xF, false);
  return v + __builtin_bit_cast(float, moved);
}

// Wave64 total, returned wave-uniform (SGPR via readlane 63).
__device__ __forceinline__ float wave_sum_uniform(float v) {
  v = dpp_add<0x128>(v);  // row_ror:8
  v = dpp_add<0x124>(v);  // row_ror:4
  v = dpp_add<0x122>(v);  // row_ror:2
  v = dpp_add<0x121>(v);  // row_ror:1
  v = dpp_add<0x142>(v);  // row_bcast:15
  v = dpp_add<0x143>(v);  // row_bcast:31
  return __builtin_bit_cast(float, __builtin_amdgcn_readlane(__builtin_bit_cast(int, v), 63));
}

__device__ __forceinline__ float lane_bcast(float v, int s) {
  return __builtin_bit_cast(float, __builtin_amdgcn_readlane(__builtin_bit_cast(int, v), s));
}

__global__ __launch_bounds__(64) void lstm_wave_kernel(
    const float* __restrict__ x,     // [B, T]
    const float* __restrict__ Wih,   // [L, 1024]
    const float* __restrict__ Whh,   // [L, 1024]
    const float* __restrict__ bih,   // [L, 1024]
    const float* __restrict__ bhh,   // [L, 1024]
    const float* __restrict__ Whr,   // [L, 256]
    float* __restrict__ seq,         // [L, B, T] layer outputs (workspace)
    int* __restrict__ flags)         // [L, B] chunk progress counters
{
  const int bid  = blockIdx.x;
  const int l    = bid >> 7;   // bid / 128
  const int b    = bid & 127;  // bid % 128
  const int lane = threadIdx.x;

  // per-lane weights, pre-scaled into the exp2 domain.
  // gate order: 0=i, 1=f, 2=g(tanh), 3=o.  E[g] = exp2(sc*(pre-activation))
  // with sc = -log2e for sigmoid gates, -2log2e for the tanh gate.
  float wix[4][4], whx[4][4], gb[4][4], whr[4], cc[4];
  const int base = l * 1024;
#pragma unroll
  for (int g = 0; g < 4; ++g) {
    const float sc = (g == 2) ? (-2.0f * LOG2E) : (-LOG2E);
#pragma unroll
    for (int k = 0; k < 4; ++k) {
      int j = base + g * 256 + k * 64 + lane;
      wix[g][k] = Wih[j] * sc;
      whx[g][k] = Whh[j] * sc;
      gb[g][k]  = (bih[j] + bhh[j]) * sc;
    }
  }
#pragma unroll
  for (int k = 0; k < 4; ++k) {
    whr[k] = Whr[l * 256 + k * 64 + lane];
    cc[k] = 0.0f;  // scaled cell state: cc = -2*log2e * c
  }

  const float* in  = (l == 0) ? (x + b * TT) : (seq + ((l - 1) * BATCH + b) * TT);
  float*       out = seq + (l * BATCH + b) * TT;
  int*       my_flag = flags + l * BATCH + b;
  const int* in_flag = (l > 0) ? (flags + (l - 1) * BATCH + b) : (const int*)flags;

  const float P2C = 2.0f * LOG2E;

  float h = 0.0f;
  for (int c = 0; c < NCH; ++c) {
    if (l > 0) {
      while (__hip_atomic_load(in_flag, __ATOMIC_ACQUIRE,
                               __HIP_MEMORY_SCOPE_AGENT) <= c)
        __builtin_amdgcn_s_sleep(2);
    }
    float xv = 0.0f;
    if (lane < CH) {
      if (l == 0)
        xv = in[c * CH + lane];
      else
        xv = __hip_atomic_load(in + c * CH + lane, __ATOMIC_RELAXED,
                               __HIP_MEMORY_SCOPE_AGENT);
    }

    float outv = 0.0f;
#pragma unroll 2
    for (int s = 0; s < CH; ++s) {
      const float xs = lane_bcast(xv, s);

      // phase A: h-independent part of all 16 pre-activations
      float gx[4][4];
#pragma unroll
      for (int g = 0; g < 4; ++g)
#pragma unroll
        for (int k = 0; k < 4; ++k)
          gx[g][k] = fmaf(xs, wix[g][k], gb[g][k]);

      // phase B: one fmaf from h, then exp2 (all 16 independent)
      float E[4][4];
#pragma unroll
      for (int g = 0; g < 4; ++g)
#pragma unroll
        for (int k = 0; k < 4; ++k)
          E[g][k] = fast_exp2(fmaf(h, whx[g][k], gx[g][k]));

      // phase D with merged reciprocals (k's independent):
      //   i*g       = (1-E2)/[(1+E0)(1+E2)]   (1 rcp instead of 2)
      //   o*tanh(c) = (1-Et)/[(1+E3)(1+Et)]   (1 rcp instead of 2)
      float rr[4];
#pragma unroll
      for (int k = 0; k < 4; ++k) {
        float A0 = 1.0f + E[0][k];
        float A1 = 1.0f + E[1][k];
        float A2 = 1.0f + E[2][k];
        float A3 = 1.0f + E[3][k];
        float fg  = fast_rcp(A1);                  // f
        float D02 = fast_rcp(A0 * A2);
        float t2  = fmaf(P2C, E[2][k], -P2C);      // -2log2e*(1-E2)
        cc[k] = fmaf(fg, cc[k], t2 * D02);         // cc = -2log2e * c
        float Et  = fast_exp2(cc[k]);              // e^{-2c}
        float D3t = fast_rcp(A3 * (1.0f + Et));
        rr[k] = fmaf(-Et, whr[k], whr[k]) * D3t;   // o*tanh(c)*whr
      }
      float r = (rr[0] + rr[1]) + (rr[2] + rr[3]);

      h = wave_sum_uniform(r);     // SGPR-uniform h(t)
      if (lane == s) outv = h;
    }

    if (l < 4) {
      if (lane < CH)
        __hip_atomic_store(out + c * CH + lane, outv, __ATOMIC_RELAXED,
                           __HIP_MEMORY_SCOPE_AGENT);
      if (lane == 0)
        __hip_atomic_store(my_flag, c + 1, __ATOMIC_RELEASE,
                           __HIP_MEMORY_SCOPE_AGENT);
    } else {
      if (lane < CH) out[c * CH + lane] = outv;  // consumed by next launch
    }
  }
}

__global__ __launch_bounds__(256) void mlp_head_kernel(
    const float* __restrict__ seq4,  // [B, T] layer-4 outputs
    const float* __restrict__ W1, const float* __restrict__ b1,
    const float* __restrict__ W2, const float* __restrict__ b2,
    const float* __restrict__ W3, const float* __restrict__ b3,
    const float* __restrict__ W4, const float* __restrict__ b4,
    float* __restrict__ out)         // [B]
{
  __shared__ float sx[TT];
  __shared__ float sh[100];
  __shared__ float sh2[100];
  __shared__ float part[100];
  __shared__ float red[4];

  const int b = blockIdx.x, tid = threadIdx.x;
  for (int i = tid; i < TT; i += 256) sx[i] = seq4[b * TT + i];
  __syncthreads();

  // phase 1: 2 threads per output (tid<100: t in [0,500); tid in [128,228): [500,1000))
  const int half = (tid >= 128) ? 1 : 0;
  const int oid  = half ? (tid - 128) : tid;
  float myacc = 0.0f;
  if (oid < 100) {
    const float* w  = W1 + oid * TT + half * 500;
    const float* xx = sx + half * 500;
    float a0 = 0.f, a1 = 0.f, a2 = 0.f, a3 = 0.f;
    for (int t0 = 0; t0 < 500; t0 += 4) {
      float4 v = *(const float4*)(w + t0);
      a0 = fmaf(v.x, xx[t0 + 0], a0);
      a1 = fmaf(v.y, xx[t0 + 1], a1);
      a2 = fmaf(v.z, xx[t0 + 2], a2);
      a3 = fmaf(v.w, xx[t0 + 3], a3);
    }
    myacc = (a0 + a1) + (a2 + a3);
    if (half) part[oid] = myacc;
  }
  __syncthreads();
  if (tid < 100) sh[tid] = fast_sigmoid(myacc + part[tid] + b1[tid]);
  __syncthreads();

  if (tid < 100) {
    float acc = b2[tid];
    const float* w = W2 + tid * 100;
    for (int k = 0; k < 100; ++k) acc += w[k] * sh[k];
    sh2[tid] = fast_sigmoid(acc);
  }
  __syncthreads();

  if (tid < 100) {
    float acc = b3[tid];
    const float* w = W3 + tid * 100;
    for (int k = 0; k < 100; ++k) acc += w[k] * sh2[k];
    sh[tid] = fmaxf(acc, 0.0f);
  }
  __syncthreads();

  float r = (tid < 100) ? sh[tid] * W4[tid] : 0.0f;
  r = dpp_add<0x128>(r);
  r = dpp_add<0x124>(r);
  r = dpp_add<0x122>(r);
  r = dpp_add<0x121>(r);
  r = dpp_add<0x142>(r);
  r = dpp_add<0x143>(r);
  r = __builtin_bit_cast(float, __builtin_amdgcn_readlane(__builtin_bit_cast(int, r), 63));
  if ((tid & 63) == 0) red[tid >> 6] = r;
  __syncthreads();
  if (tid == 0) out[b] = (red[0] + red[1]) + (red[2] + red[3]) + b4[0];
}

extern "C" void kernel_launch(void* const* d_in, const int* in_sizes, int n_in,
                              void* d_out, int out_size, void* d_ws, size_t ws_size,
                              hipStream_t stream) {
  const float* x   = (const float*)d_in[0];
  const float* Wih = (const float*)d_in[1];
  const float* Whh = (const float*)d_in[2];
  const float* bih = (const float*)d_in[3];
  const float* bhh = (const float*)d_in[4];
  const float* Whr = (const float*)d_in[5];
  const float* W1  = (const float*)d_in[6];
  const float* b1  = (const float*)d_in[7];
  const float* W2  = (const float*)d_in[8];
  const float* b2  = (const float*)d_in[9];
  const float* W3  = (const float*)d_in[10];
  const float* b3  = (const float*)d_in[11];
  const float* W4  = (const float*)d_in[12];
  const float* b4  = (const float*)d_in[13];

  float* seq   = (float*)d_ws;                       // [5][128][1000] f32 = 2.56 MB
  int*   flags = (int*)(seq + LAYERS * BATCH * TT);  // [5][128] int

  hipMemsetAsync(flags, 0, LAYERS * BATCH * sizeof(int), stream);
  lstm_wave_kernel<<<LAYERS * BATCH, 64, 0, stream>>>(x, Wih, Whh, bih, bhh, Whr,
                                                      seq, flags);
  mlp_head_kernel<<<BATCH, 256, 0, stream>>>(seq + 4 * BATCH * TT,
                                             W1, b1, W2, b2, W3, b3, W4, b4,
                                             (float*)d_out);
}